// Round 3
// baseline (263.083 us; speedup 1.0000x reference)
//
#include <hip/hip_runtime.h>

// SpatialEncoding: out[src,dst] = b[min(path_len,5)-1], last-write-wins in p order.
//
// R12: R11 + rank-reuse in bin (single-atomic counting sort).
//   KA se_bin_local : Phase A histogram atomicAdd RETURNS the record's
//                     within-bucket rank; rank (<2^14) is packed into the 14
//                     spare high bits of lows[k]. Phase D is then PURE LDS
//                     stores at start[bucket]+rank -- the 8M cursor atomics
//                     of R11 are gone (LDS atomic traffic halved).
//                     Within-run record order changes (atomic order vs p
//                     order) -- irrelevant: merge orders by local_p key.
//   KB se_transpose : [nblk][2200] u16 local starts -> T[2199][nblk] u16.
//   KC se_merge2    : per-bucket 64KB LDS atomicMax merge; run bounds loaded
//                     BEFORE the LDS zero (latency hidden under fill loop);
//                     aligned uint4 run walk predicated by position.
//                     key = (tr<<18)|(rec&0x3FFFF) restores global p order.
//                     Bijective XCD swizzle on c for L2 line sharing.
//   Fallback path (small ws): R9 pipeline verbatim.
//
//   rec(u32) = off(14 bits [31:18]) | (local_p+1)(15 bits [17:3]) | clamped(3)
//   merge key = (blk_rank(10) << 18) | (rec & 0x3FFFF)  (28 bits, >0 always)

#define BSHIFT 14
#define BCELLS (1 << BSHIFT)            // 16384 cells per bucket (64 KB region)
#define NBUCK  2198                     // ceil(36e6 / 16384)
#define NPACK  1100                     // ceil(NBUCK/2)+pad (in-bounds for owners)
#define NOWN   550                      // owner threads, 4 buckets each
#define BIN_THREADS 1024
#define TILE   12288                    // pairs per bin block
#define SCAN_TB 16                      // buckets per scan block (fallback)
#define MAXBLK 656                      // >= ceil(8e6/12288)=652
#define MRG_THREADS 1024

__device__ __forceinline__ unsigned int unpack16(const unsigned int* A, unsigned int c) {
    return (A[c >> 1] >> ((c & 1) * 16)) & 0xFFFFu;
}

// ======================= FAST PATH =======================

// ---------------- KA: single-pass local binning (rank-reuse) ----------------
__global__ __launch_bounds__(BIN_THREADS) void se_bin_local(
        const int* __restrict__ src_idx,
        const int* __restrict__ dst_idx,
        const int* __restrict__ path_len,
        unsigned int* __restrict__ recs,        // ws: [nblk][TILE] u32
        unsigned int* __restrict__ startsW,     // ws: [nblk][NPACK] u32 (u16 pairs)
        int P, int n) {
    __shared__ unsigned int histP[NPACK];       // local run starts (packed u16)
    __shared__ unsigned int curP[NPACK];        // counts
    __shared__ unsigned int stage[TILE];        // 48 KB u32 staging
    __shared__ unsigned int scr[34];

    int t = threadIdx.x;
    int start = blockIdx.x * TILE;

    for (int i = t; i < NPACK; i += BIN_THREADS) curP[i] = 0u;
    __syncthreads();

    // Phase A: read 12 pairs/thread (int4 x3), build cell + low-18 key
    int cells[12];
    unsigned int lows[12];
#pragma unroll
    for (int j = 0; j < 3; ++j) {
        int base = start + j * (BIN_THREADS * 4) + t * 4;
        int k0 = j * 4;
        if (base + 3 < P) {
            int4 s = *reinterpret_cast<const int4*>(src_idx + base);
            int4 d = *reinterpret_cast<const int4*>(dst_idx + base);
            int4 l = *reinterpret_cast<const int4*>(path_len + base);
            int lp = base - start;                     // local pair index
            cells[k0]     = s.x * n + d.x;
            cells[k0 + 1] = s.y * n + d.y;
            cells[k0 + 2] = s.z * n + d.z;
            cells[k0 + 3] = s.w * n + d.w;
            lows[k0]     = ((unsigned int)(lp + 1) << 3) | (unsigned int)((l.x < 5 ? l.x : 5) - 1);
            lows[k0 + 1] = ((unsigned int)(lp + 2) << 3) | (unsigned int)((l.y < 5 ? l.y : 5) - 1);
            lows[k0 + 2] = ((unsigned int)(lp + 3) << 3) | (unsigned int)((l.z < 5 ? l.z : 5) - 1);
            lows[k0 + 3] = ((unsigned int)(lp + 4) << 3) | (unsigned int)((l.w < 5 ? l.w : 5) - 1);
        } else {
#pragma unroll
            for (int jj = 0; jj < 4; ++jj) {
                int p = base + jj;
                if (p < P) {
                    cells[k0 + jj] = src_idx[p] * n + dst_idx[p];
                    int len = path_len[p];
                    int cl = (len < 5 ? len : 5) - 1;
                    lows[k0 + jj] = ((unsigned int)(p - start + 1) << 3) | (unsigned int)cl;
                } else {
                    cells[k0 + jj] = -1;
                    lows[k0 + jj] = 0u;
                }
            }
        }
    }
    // Histogram: atomicAdd return value = within-bucket rank; pack into
    // lows[31:18] (rank < TILE=12288 < 2^14). No second atomic pass needed.
#pragma unroll
    for (int k = 0; k < 12; ++k) {
        if (cells[k] >= 0) {
            unsigned int c = (unsigned int)cells[k] >> BSHIFT;
            unsigned int old = atomicAdd(&curP[c >> 1], (c & 1) ? 0x10000u : 1u);
            unsigned int rank = (old >> ((c & 1) * 16)) & 0xFFFFu;
            lows[k] |= rank << 18;
        }
    }
    __syncthreads();

    // Phase B: block-wide exclusive scan of counts -> local run starts (histP)
    unsigned int l0 = 0, l1 = 0, l2v = 0, l3 = 0, s = 0;
    if (t < NOWN) {
        unsigned int w0 = curP[2 * t], w1 = curP[2 * t + 1];
        unsigned int v0 = w0 & 0xFFFFu, v1 = w0 >> 16;
        unsigned int v2 = w1 & 0xFFFFu, v3 = w1 >> 16;
        l0 = 0; l1 = v0; l2v = v0 + v1; l3 = v0 + v1 + v2;
        s = v0 + v1 + v2 + v3;
    }
    unsigned int x = s;
    for (int d = 1; d < 64; d <<= 1) {
        unsigned int y = (unsigned int)__shfl_up((int)x, d, 64);
        if ((t & 63) >= d) x += y;
    }
    if ((t & 63) == 63) scr[t >> 6] = x;
    __syncthreads();
    if (t == 0) {
        unsigned int acc = 0;
        for (int w = 0; w < 16; ++w) { unsigned int v = scr[w]; scr[16 + w] = acc; acc += v; }
        scr[32] = acc;
    }
    __syncthreads();
    unsigned int exc = x - s + scr[16 + (t >> 6)];
    if (t < NOWN) {
        unsigned int st0 = exc + l0, st1 = exc + l1, st2 = exc + l2v, st3 = exc + l3;
        histP[2 * t]     = (st0 & 0xFFFFu) | (st1 << 16);
        histP[2 * t + 1] = (st2 & 0xFFFFu) | (st3 << 16);
    }
    __syncthreads();

    // Phase C': persist local starts (coalesced)
    for (int i = t; i < NPACK; i += BIN_THREADS)
        startsW[(size_t)blockIdx.x * NPACK + i] = histP[i];

    // Phase D': place records -- PURE stores at start[bucket] + rank
#pragma unroll
    for (int k = 0; k < 12; ++k) {
        if (cells[k] >= 0) {
            unsigned int cell = (unsigned int)cells[k];
            unsigned int c = cell >> BSHIFT;
            unsigned int pos = unpack16(histP, c) + (lows[k] >> 18);
            stage[pos] = ((cell & (BCELLS - 1)) << 18) | (lows[k] & 0x3FFFFu);
        }
    }
    __syncthreads();

    // Phase E': LINEAR coalesced b128 flush of the staged tile
    unsigned int tot = scr[32];
    unsigned int* dst = recs + (size_t)blockIdx.x * TILE;
    const uint4* st4 = reinterpret_cast<const uint4*>(stage);
    uint4* dst4 = reinterpret_cast<uint4*>(dst);
    if (tot == TILE) {
        // full tile: fixed trip count (3 iters), unrollable
#pragma unroll
        for (int j = 0; j < TILE / 4 / BIN_THREADS; ++j)
            dst4[j * BIN_THREADS + t] = st4[j * BIN_THREADS + t];
    } else {
        unsigned int tot4 = tot >> 2;
        for (unsigned int i = t; i < tot4; i += BIN_THREADS)
            dst4[i] = st4[i];
        for (unsigned int i = (tot4 << 2) + t; i < tot; i += BIN_THREADS)
            dst[i] = stage[i];
    }
}

// ---------------- KB: transpose local starts ----------------
__global__ __launch_bounds__(256) void se_transpose(
        const unsigned int* __restrict__ startsW,   // [nblk][NPACK] u32 (u16 pairs)
        unsigned short* __restrict__ T,             // [NBUCK+1][nblk] u16
        int nblk) {
    __shared__ unsigned short tile[64][66];         // 64 buckets x 64 blks (+pad)
    int bc0 = blockIdx.x * 64;                      // bucket base
    int bb0 = blockIdx.y * 64;                      // blk base

    for (int i = threadIdx.x; i < 64 * 32; i += 256) {
        int r = i >> 5;                             // blk offset 0..63
        int w = i & 31;                             // word offset 0..31
        int blk = bb0 + r;
        int word = (bc0 >> 1) + w;
        unsigned int v = 0;
        if (blk < nblk && word < NPACK)
            v = startsW[(size_t)blk * NPACK + word];
        tile[2 * w][r]     = (unsigned short)(v & 0xFFFFu);
        tile[2 * w + 1][r] = (unsigned short)(v >> 16);
    }
    __syncthreads();

    for (int i = threadIdx.x; i < 64 * 64; i += 256) {
        int c = i >> 6, bl = i & 63;
        int gc = bc0 + c, gb = bb0 + bl;
        if (gc <= NBUCK && gb < nblk)               // rows 0..NBUCK inclusive
            T[(size_t)gc * nblk + gb] = tile[c][bl];
    }
}

// ---------------- shared decode helper ----------------
__device__ __forceinline__ float se_decode(unsigned int k,
                                           float b0, float b1, float b2,
                                           float b3, float b4) {
    unsigned c = k & 7u;
    float t = (c == 0u) ? b0 : (c == 1u) ? b1 : (c == 2u) ? b2 : (c == 3u) ? b3 : b4;
    return k ? t : 0.0f;
}

// ---------------- KC: per-bucket merge, vectorized run walk ----------------
__global__ __launch_bounds__(MRG_THREADS) void se_merge2(
        const unsigned short* __restrict__ T,       // [NBUCK+1][nblk]
        const unsigned int* __restrict__ recs,      // [nblk][TILE]
        const float* __restrict__ b,
        float* __restrict__ out,
        long long totalCells, int nblk) {
    __shared__ unsigned int tab[BCELLS];            // 64 KB

    // bijective XCD swizzle: consecutive c per XCD -> adjacent runs share L2 lines
    int orig = blockIdx.x;
    int q = gridDim.x >> 3, r8 = gridDim.x & 7;
    int xcd = orig & 7, idx = orig >> 3;
    int c = (xcd < r8 ? xcd * (q + 1) : r8 * (q + 1) + (xcd - r8) * q) + idx;

    long long baseCell = (long long)c << BSHIFT;
    long long rem = totalCells - baseCell;
    int valid = rem < BCELLS ? (int)rem : BCELLS;

    // load run bounds BEFORE the LDS zero so the latency hides under it
    int tr = threadIdx.x;
    unsigned int st = 0, en = 0;
    if (tr < nblk) {
        st = T[(size_t)c * nblk + tr];
        en = T[(size_t)(c + 1) * nblk + tr];
    }

    uint4* tab4 = reinterpret_cast<uint4*>(tab);
    for (int i = threadIdx.x; i < BCELLS / 4; i += MRG_THREADS)
        tab4[i] = make_uint4(0u, 0u, 0u, 0u);
    __syncthreads();

    if (tr < nblk) {
        const uint4* rp4 =
            reinterpret_cast<const uint4*>(recs + (size_t)tr * TILE);
        unsigned int keyhi = (unsigned int)tr << 18;
        // aligned uint4 walk, predicated by position; out-of-run lanes belong
        // to neighbor buckets and are skipped. i+3 <= TILE-1 always (TILE%4==0).
        for (unsigned int i = st & ~3u; i < en; i += 4) {
            uint4 r4 = rp4[i >> 2];
            if (i     >= st && i     < en) atomicMax(&tab[r4.x >> 18], keyhi | (r4.x & 0x3FFFFu));
            if (i + 1 >= st && i + 1 < en) atomicMax(&tab[r4.y >> 18], keyhi | (r4.y & 0x3FFFFu));
            if (i + 2 >= st && i + 2 < en) atomicMax(&tab[r4.z >> 18], keyhi | (r4.z & 0x3FFFFu));
            if (i + 3 >= st && i + 3 < en) atomicMax(&tab[r4.w >> 18], keyhi | (r4.w & 0x3FFFFu));
        }
    }
    __syncthreads();

    float b0 = b[0], b1 = b[1], b2 = b[2], b3 = b[3], b4 = b[4];
    float* o = out + baseCell;
    int n4 = valid >> 2;
    float4* o4 = reinterpret_cast<float4*>(o);
    for (int i = threadIdx.x; i < n4; i += MRG_THREADS) {
        uint4 k = tab4[i];
        float4 v;
        v.x = se_decode(k.x, b0, b1, b2, b3, b4);
        v.y = se_decode(k.y, b0, b1, b2, b3, b4);
        v.z = se_decode(k.z, b0, b1, b2, b3, b4);
        v.w = se_decode(k.w, b0, b1, b2, b3, b4);
        o4[i] = v;
    }
    for (int i = (n4 << 2) + threadIdx.x; i < valid; i += MRG_THREADS)
        o[i] = se_decode(tab[i], b0, b1, b2, b3, b4);
}

// ======================= FALLBACK PATH (R9, verbatim) =======================

__global__ __launch_bounds__(BIN_THREADS) void se_hist(
        const int* __restrict__ src_idx,
        const int* __restrict__ dst_idx,
        unsigned int* __restrict__ countsW,      // [nblk][NPACK] u32 (u16 pairs)
        int P, int n) {
    __shared__ unsigned int curP[NPACK];
    int t = threadIdx.x;
    for (int i = t; i < NPACK; i += BIN_THREADS) curP[i] = 0u;
    __syncthreads();

    int start = blockIdx.x * TILE;
#pragma unroll
    for (int j = 0; j < 3; ++j) {
        int base = start + j * (BIN_THREADS * 4) + t * 4;
        if (base + 3 < P) {
            int4 s = *reinterpret_cast<const int4*>(src_idx + base);
            int4 d = *reinterpret_cast<const int4*>(dst_idx + base);
            unsigned int c0 = (unsigned int)(s.x * n + d.x) >> BSHIFT;
            unsigned int c1 = (unsigned int)(s.y * n + d.y) >> BSHIFT;
            unsigned int c2 = (unsigned int)(s.z * n + d.z) >> BSHIFT;
            unsigned int c3 = (unsigned int)(s.w * n + d.w) >> BSHIFT;
            atomicAdd(&curP[c0 >> 1], (c0 & 1) ? 0x10000u : 1u);
            atomicAdd(&curP[c1 >> 1], (c1 & 1) ? 0x10000u : 1u);
            atomicAdd(&curP[c2 >> 1], (c2 & 1) ? 0x10000u : 1u);
            atomicAdd(&curP[c3 >> 1], (c3 & 1) ? 0x10000u : 1u);
        } else {
            for (int p = base; p < P && p < base + 4; ++p) {
                unsigned int c = (unsigned int)(src_idx[p] * n + dst_idx[p]) >> BSHIFT;
                atomicAdd(&curP[c >> 1], (c & 1) ? 0x10000u : 1u);
            }
        }
    }
    __syncthreads();
    for (int i = t; i < NPACK; i += BIN_THREADS)
        countsW[(size_t)blockIdx.x * NPACK + i] = curP[i];
}

__global__ __launch_bounds__(256) void se_scan(
        unsigned int* __restrict__ countsW,   // in: counts, out: bases (in place)
        unsigned short* __restrict__ basesT,  // [NBUCK][nblk+1] u16, sentinel=total
        int nblk) {
    __shared__ unsigned short lds16[MAXBLK * SCAN_TB];   // 21 KB
    unsigned int* lds32 = reinterpret_cast<unsigned int*>(lds16);
    int t = threadIdx.x;
    int c0 = blockIdx.x * SCAN_TB;
    int w0 = c0 >> 1;
    int words = nblk * (SCAN_TB / 2);

    for (int i = t; i < words; i += 256) {
        int r = i >> 3, w = i & 7;
        if (w0 + w < NPACK)
            lds32[r * 8 + w] = countsW[(size_t)r * NPACK + w0 + w];
    }
    __syncthreads();

    if (t < SCAN_TB && c0 + t < NBUCK) {
        unsigned int acc = 0;
        for (int r = 0; r < nblk; ++r) {
            unsigned short v = lds16[r * SCAN_TB + t];
            lds16[r * SCAN_TB + t] = (unsigned short)acc;
            acc += v;
        }
        basesT[(size_t)(c0 + t) * (nblk + 1) + nblk] = (unsigned short)acc;
    }
    __syncthreads();

    for (int i = t; i < words; i += 256) {
        int r = i >> 3, w = i & 7;
        if (w0 + w < NPACK)
            countsW[(size_t)r * NPACK + w0 + w] = lds32[r * 8 + w];
    }
    for (int k = 0; k < SCAN_TB; ++k) {
        int c = c0 + k;
        if (c >= NBUCK) break;
        for (int r = t; r < nblk; r += 256)
            basesT[(size_t)c * (nblk + 1) + r] = lds16[r * SCAN_TB + k];
    }
}

__global__ __launch_bounds__(BIN_THREADS) void se_bin5(
        const int* __restrict__ src_idx,
        const int* __restrict__ dst_idx,
        const int* __restrict__ path_len,
        unsigned int* __restrict__ recs,         // d_out viewed as u32
        const unsigned int* __restrict__ basesW, // countsW after scan (u16 pairs)
        int P, int n) {
    __shared__ unsigned int histP[NPACK];
    __shared__ unsigned int curP[NPACK];
    __shared__ unsigned int gbaseP[NPACK];
    __shared__ unsigned int stage[TILE];
    __shared__ unsigned int scr[34];

    int t = threadIdx.x;
    int start = blockIdx.x * TILE;

    for (int i = t; i < NPACK; i += BIN_THREADS) curP[i] = 0u;
    __syncthreads();

    int cells[12];
    unsigned int lows[12];
#pragma unroll
    for (int j = 0; j < 3; ++j) {
        int base = start + j * (BIN_THREADS * 4) + t * 4;
        int k0 = j * 4;
        if (base + 3 < P) {
            int4 s = *reinterpret_cast<const int4*>(src_idx + base);
            int4 d = *reinterpret_cast<const int4*>(dst_idx + base);
            int4 l = *reinterpret_cast<const int4*>(path_len + base);
            int lp = base - start;
            cells[k0]     = s.x * n + d.x;
            cells[k0 + 1] = s.y * n + d.y;
            cells[k0 + 2] = s.z * n + d.z;
            cells[k0 + 3] = s.w * n + d.w;
            lows[k0]     = ((unsigned int)(lp + 1) << 3) | (unsigned int)((l.x < 5 ? l.x : 5) - 1);
            lows[k0 + 1] = ((unsigned int)(lp + 2) << 3) | (unsigned int)((l.y < 5 ? l.y : 5) - 1);
            lows[k0 + 2] = ((unsigned int)(lp + 3) << 3) | (unsigned int)((l.z < 5 ? l.z : 5) - 1);
            lows[k0 + 3] = ((unsigned int)(lp + 4) << 3) | (unsigned int)((l.w < 5 ? l.w : 5) - 1);
        } else {
#pragma unroll
            for (int jj = 0; jj < 4; ++jj) {
                int p = base + jj;
                if (p < P) {
                    cells[k0 + jj] = src_idx[p] * n + dst_idx[p];
                    int len = path_len[p];
                    int cl = (len < 5 ? len : 5) - 1;
                    lows[k0 + jj] = ((unsigned int)(p - start + 1) << 3) | (unsigned int)cl;
                } else {
                    cells[k0 + jj] = -1;
                    lows[k0 + jj] = 0u;
                }
            }
        }
    }
#pragma unroll
    for (int k = 0; k < 12; ++k) {
        if (cells[k] >= 0) {
            unsigned int c = (unsigned int)cells[k] >> BSHIFT;
            atomicAdd(&curP[c >> 1], (c & 1) ? 0x10000u : 1u);
        }
    }
    __syncthreads();

    unsigned int l0 = 0, l1 = 0, l2v = 0, l3 = 0, s = 0;
    if (t < NOWN) {
        unsigned int w0 = curP[2 * t], w1 = curP[2 * t + 1];
        unsigned int v0 = w0 & 0xFFFFu, v1 = w0 >> 16;
        unsigned int v2 = w1 & 0xFFFFu, v3 = w1 >> 16;
        l0 = 0; l1 = v0; l2v = v0 + v1; l3 = v0 + v1 + v2;
        s = v0 + v1 + v2 + v3;
    }
    unsigned int x = s;
    for (int d = 1; d < 64; d <<= 1) {
        unsigned int y = (unsigned int)__shfl_up((int)x, d, 64);
        if ((t & 63) >= d) x += y;
    }
    if ((t & 63) == 63) scr[t >> 6] = x;
    __syncthreads();
    if (t == 0) {
        unsigned int acc = 0;
        for (int w = 0; w < 16; ++w) { unsigned int v = scr[w]; scr[16 + w] = acc; acc += v; }
        scr[32] = acc;
    }
    __syncthreads();
    unsigned int exc = x - s + scr[16 + (t >> 6)];
    if (t < NOWN) {
        unsigned int st0 = exc + l0, st1 = exc + l1, st2 = exc + l2v, st3 = exc + l3;
        histP[2 * t]     = (st0 & 0xFFFFu) | (st1 << 16);
        histP[2 * t + 1] = (st2 & 0xFFFFu) | (st3 << 16);
    }
    __syncthreads();

    for (int i = t; i < NPACK; i += BIN_THREADS) {
        gbaseP[i] = basesW[(size_t)blockIdx.x * NPACK + i];
        curP[i] = histP[i];
    }
    __syncthreads();

#pragma unroll
    for (int k = 0; k < 12; ++k) {
        if (cells[k] >= 0) {
            unsigned int cell = (unsigned int)cells[k];
            unsigned int c = cell >> BSHIFT;
            unsigned int old = atomicAdd(&curP[c >> 1], (c & 1) ? 0x10000u : 1u);
            unsigned int pos = (old >> ((c & 1) * 16)) & 0xFFFFu;
            stage[pos] = ((cell & (BCELLS - 1)) << 18) | lows[k];
        }
    }
    __syncthreads();

    unsigned int tot = scr[32];
    for (unsigned int i = t; i < tot; i += BIN_THREADS) {
        unsigned int rec = stage[i];
        unsigned int lo = 0, hi = 2199;
        while (lo < hi) {
            unsigned int mid = (lo + hi + 1) >> 1;
            if (unpack16(histP, mid) <= i) lo = mid; else hi = mid - 1;
        }
        unsigned int c = lo;
        unsigned int pos = unpack16(gbaseP, c) + (i - unpack16(histP, c));
        recs[(size_t)c * BCELLS + pos] = rec;
    }
}

__global__ __launch_bounds__(MRG_THREADS) void se_merge(
        const unsigned short* __restrict__ basesT,  // [NBUCK][nblk+1]
        const float* __restrict__ b,
        float* __restrict__ out,              // same memory as recs
        long long totalCells, int nblk) {
    __shared__ unsigned int tab[BCELLS];

    int c = blockIdx.x;
    long long baseCell = (long long)c << BSHIFT;
    long long rem = totalCells - baseCell;
    int valid = rem < BCELLS ? (int)rem : BCELLS;

    uint4* tab4 = reinterpret_cast<uint4*>(tab);
    for (int i = threadIdx.x; i < BCELLS / 4; i += MRG_THREADS)
        tab4[i] = make_uint4(0u, 0u, 0u, 0u);
    __syncthreads();

    const unsigned int* r =
        reinterpret_cast<const unsigned int*>(out) + (size_t)c * BCELLS;
    int tr = threadIdx.x;
    if (tr < nblk) {
        const unsigned short* B = basesT + (size_t)c * (nblk + 1);
        unsigned int rb0 = B[tr], rb1 = B[tr + 1];
        unsigned int keyhi = (unsigned int)tr << 18;
        for (unsigned int i = rb0; i < rb1; ++i) {
            unsigned int rec = r[i];
            atomicMax(&tab[rec >> 18], keyhi | (rec & 0x3FFFFu));
        }
    }
    __syncthreads();

    float b0 = b[0], b1 = b[1], b2 = b[2], b3 = b[3], b4 = b[4];
    float* o = out + baseCell;
    int n4 = valid >> 2;
    float4* o4 = reinterpret_cast<float4*>(o);
    for (int i = threadIdx.x; i < n4; i += MRG_THREADS) {
        uint4 k = tab4[i];
        float4 v;
        v.x = se_decode(k.x, b0, b1, b2, b3, b4);
        v.y = se_decode(k.y, b0, b1, b2, b3, b4);
        v.z = se_decode(k.z, b0, b1, b2, b3, b4);
        v.w = se_decode(k.w, b0, b1, b2, b3, b4);
        o4[i] = v;
    }
    for (int i = (n4 << 2) + threadIdx.x; i < valid; i += MRG_THREADS)
        o[i] = se_decode(tab[i], b0, b1, b2, b3, b4);
}

// ======================= launch =======================

extern "C" void kernel_launch(void* const* d_in, const int* in_sizes, int n_in,
                              void* d_out, int out_size, void* d_ws, size_t ws_size,
                              hipStream_t stream) {
    // inputs: 0=x [N*128 f32], 1=b [5 f32], 2=src_idx [P i32], 3=dst_idx [P i32], 4=path_len [P i32]
    const float* b        = (const float*)d_in[1];
    const int*   src_idx  = (const int*)d_in[2];
    const int*   dst_idx  = (const int*)d_in[3];
    const int*   path_len = (const int*)d_in[4];
    int P = in_sizes[2];
    int n = in_sizes[0] / 128;                      // N = 6000
    long long totalCells = (long long)n * n;        // 36,000,000
    int nblk = (P + TILE - 1) / TILE;               // 652

    // Fast path ws layout: recs [nblk*TILE u32] (30.6 MB) |
    //                      startsW [nblk*NPACK u32] (2.9 MB) |
    //                      T [(NBUCK+1)*nblk u16] (2.9 MB)
    size_t needFast = (size_t)nblk * TILE * 4u
                    + (size_t)nblk * NPACK * 4u
                    + (size_t)(NBUCK + 1) * nblk * 2u;

    if (ws_size >= needFast && nblk <= MRG_THREADS) {
        unsigned int*   recs    = (unsigned int*)d_ws;
        unsigned int*   startsW = recs + (size_t)nblk * TILE;
        unsigned short* T       = (unsigned short*)(startsW + (size_t)nblk * NPACK);

        se_bin_local<<<nblk, BIN_THREADS, 0, stream>>>(
            src_idx, dst_idx, path_len, recs, startsW, P, n);

        dim3 tg((NBUCK + 1 + 63) / 64, (nblk + 63) / 64);
        se_transpose<<<tg, 256, 0, stream>>>(startsW, T, nblk);

        se_merge2<<<NBUCK, MRG_THREADS, 0, stream>>>(
            T, recs, b, (float*)d_out, totalCells, nblk);
    } else {
        // R9 fallback: records staged in d_out at global per-bucket bases
        unsigned int*   countsW = (unsigned int*)d_ws;
        unsigned short* basesT  = (unsigned short*)(countsW + (size_t)nblk * NPACK);

        se_hist<<<nblk, BIN_THREADS, 0, stream>>>(src_idx, dst_idx, countsW, P, n);
        se_scan<<<(NBUCK + SCAN_TB - 1) / SCAN_TB, 256, 0, stream>>>(countsW, basesT, nblk);
        se_bin5<<<nblk, BIN_THREADS, 0, stream>>>(
            src_idx, dst_idx, path_len, (unsigned int*)d_out, countsW, P, n);
        se_merge<<<NBUCK, MRG_THREADS, 0, stream>>>(basesT, b, (float*)d_out,
                                                    totalCells, nblk);
    }
}

// Round 4
// 262.944 us; speedup vs baseline: 1.0005x; 1.0005x over previous
//
#include <hip/hip_runtime.h>

// SpatialEncoding: out[src,dst] = b[min(path_len,5)-1], last-write-wins in p order.
//
// R13: R12 minus transpose kernel, plus merge run-splitting.
//   KA se_bin_local : unchanged from R12 (single-atomic counting sort; rank
//                     from histogram atomicAdd packed into lows[31:18];
//                     Phase D pure stores; linear b128 flush).
//   KC se_merge3    : per-bucket 64KB LDS atomicMax merge.
//                     - run bounds read DIRECTLY from startsW (u16 pairs,
//                       2.9MB => L2-resident; uncoalesced reads hidden under
//                       the LDS zero fill). Transpose kernel DELETED.
//                     - run-splitting: owner threads (tr<nblk) with len>=8
//                       take an LDS ticket; helper threads (tr>=nblk, 372
//                       idle otherwise) process [mid,en) of ticketed runs.
//                       Wave-max walk length ~14 -> ~7 records.
//                     - aligned uint4 walk predicated by position (R11).
//                     key = (blk_rank<<18)|(rec&0x3FFFF) restores p order.
//                     Bijective XCD swizzle on c for L2 line sharing.
//   Fallback path (small ws): R9 pipeline verbatim.
//
//   rec(u32) = off(14 bits [31:18]) | (local_p+1)(15 bits [17:3]) | clamped(3)
//   merge key = (blk_rank(10) << 18) | (rec & 0x3FFFF)  (28 bits, >0 always)

#define BSHIFT 14
#define BCELLS (1 << BSHIFT)            // 16384 cells per bucket (64 KB region)
#define NBUCK  2198                     // ceil(36e6 / 16384)
#define NPACK  1100                     // ceil(NBUCK/2)+pad (in-bounds for owners)
#define NOWN   550                      // owner threads, 4 buckets each
#define BIN_THREADS 1024
#define TILE   12288                    // pairs per bin block
#define SCAN_TB 16                      // buckets per scan block (fallback)
#define MAXBLK 656                      // >= ceil(8e6/12288)=652
#define MRG_THREADS 1024
#define HMAXE  512                      // helper entry table capacity

__device__ __forceinline__ unsigned int unpack16(const unsigned int* A, unsigned int c) {
    return (A[c >> 1] >> ((c & 1) * 16)) & 0xFFFFu;
}

// ======================= FAST PATH =======================

// ---------------- KA: single-pass local binning (rank-reuse) ----------------
__global__ __launch_bounds__(BIN_THREADS) void se_bin_local(
        const int* __restrict__ src_idx,
        const int* __restrict__ dst_idx,
        const int* __restrict__ path_len,
        unsigned int* __restrict__ recs,        // ws: [nblk][TILE] u32
        unsigned int* __restrict__ startsW,     // ws: [nblk][NPACK] u32 (u16 pairs)
        int P, int n) {
    __shared__ unsigned int histP[NPACK];       // local run starts (packed u16)
    __shared__ unsigned int curP[NPACK];        // counts
    __shared__ unsigned int stage[TILE];        // 48 KB u32 staging
    __shared__ unsigned int scr[34];

    int t = threadIdx.x;
    int start = blockIdx.x * TILE;

    for (int i = t; i < NPACK; i += BIN_THREADS) curP[i] = 0u;
    __syncthreads();

    // Phase A: read 12 pairs/thread (int4 x3), build cell + low-18 key
    int cells[12];
    unsigned int lows[12];
#pragma unroll
    for (int j = 0; j < 3; ++j) {
        int base = start + j * (BIN_THREADS * 4) + t * 4;
        int k0 = j * 4;
        if (base + 3 < P) {
            int4 s = *reinterpret_cast<const int4*>(src_idx + base);
            int4 d = *reinterpret_cast<const int4*>(dst_idx + base);
            int4 l = *reinterpret_cast<const int4*>(path_len + base);
            int lp = base - start;                     // local pair index
            cells[k0]     = s.x * n + d.x;
            cells[k0 + 1] = s.y * n + d.y;
            cells[k0 + 2] = s.z * n + d.z;
            cells[k0 + 3] = s.w * n + d.w;
            lows[k0]     = ((unsigned int)(lp + 1) << 3) | (unsigned int)((l.x < 5 ? l.x : 5) - 1);
            lows[k0 + 1] = ((unsigned int)(lp + 2) << 3) | (unsigned int)((l.y < 5 ? l.y : 5) - 1);
            lows[k0 + 2] = ((unsigned int)(lp + 3) << 3) | (unsigned int)((l.z < 5 ? l.z : 5) - 1);
            lows[k0 + 3] = ((unsigned int)(lp + 4) << 3) | (unsigned int)((l.w < 5 ? l.w : 5) - 1);
        } else {
#pragma unroll
            for (int jj = 0; jj < 4; ++jj) {
                int p = base + jj;
                if (p < P) {
                    cells[k0 + jj] = src_idx[p] * n + dst_idx[p];
                    int len = path_len[p];
                    int cl = (len < 5 ? len : 5) - 1;
                    lows[k0 + jj] = ((unsigned int)(p - start + 1) << 3) | (unsigned int)cl;
                } else {
                    cells[k0 + jj] = -1;
                    lows[k0 + jj] = 0u;
                }
            }
        }
    }
    // Histogram: atomicAdd return value = within-bucket rank; pack into
    // lows[31:18] (rank < TILE=12288 < 2^14). No second atomic pass needed.
#pragma unroll
    for (int k = 0; k < 12; ++k) {
        if (cells[k] >= 0) {
            unsigned int c = (unsigned int)cells[k] >> BSHIFT;
            unsigned int old = atomicAdd(&curP[c >> 1], (c & 1) ? 0x10000u : 1u);
            unsigned int rank = (old >> ((c & 1) * 16)) & 0xFFFFu;
            lows[k] |= rank << 18;
        }
    }
    __syncthreads();

    // Phase B: block-wide exclusive scan of counts -> local run starts (histP)
    unsigned int l0 = 0, l1 = 0, l2v = 0, l3 = 0, s = 0;
    if (t < NOWN) {
        unsigned int w0 = curP[2 * t], w1 = curP[2 * t + 1];
        unsigned int v0 = w0 & 0xFFFFu, v1 = w0 >> 16;
        unsigned int v2 = w1 & 0xFFFFu, v3 = w1 >> 16;
        l0 = 0; l1 = v0; l2v = v0 + v1; l3 = v0 + v1 + v2;
        s = v0 + v1 + v2 + v3;
    }
    unsigned int x = s;
    for (int d = 1; d < 64; d <<= 1) {
        unsigned int y = (unsigned int)__shfl_up((int)x, d, 64);
        if ((t & 63) >= d) x += y;
    }
    if ((t & 63) == 63) scr[t >> 6] = x;
    __syncthreads();
    if (t == 0) {
        unsigned int acc = 0;
        for (int w = 0; w < 16; ++w) { unsigned int v = scr[w]; scr[16 + w] = acc; acc += v; }
        scr[32] = acc;
    }
    __syncthreads();
    unsigned int exc = x - s + scr[16 + (t >> 6)];
    if (t < NOWN) {
        unsigned int st0 = exc + l0, st1 = exc + l1, st2 = exc + l2v, st3 = exc + l3;
        histP[2 * t]     = (st0 & 0xFFFFu) | (st1 << 16);
        histP[2 * t + 1] = (st2 & 0xFFFFu) | (st3 << 16);
    }
    __syncthreads();

    // Phase C': persist local starts (coalesced)
    for (int i = t; i < NPACK; i += BIN_THREADS)
        startsW[(size_t)blockIdx.x * NPACK + i] = histP[i];

    // Phase D': place records -- PURE stores at start[bucket] + rank
#pragma unroll
    for (int k = 0; k < 12; ++k) {
        if (cells[k] >= 0) {
            unsigned int cell = (unsigned int)cells[k];
            unsigned int c = cell >> BSHIFT;
            unsigned int pos = unpack16(histP, c) + (lows[k] >> 18);
            stage[pos] = ((cell & (BCELLS - 1)) << 18) | (lows[k] & 0x3FFFFu);
        }
    }
    __syncthreads();

    // Phase E': LINEAR coalesced b128 flush of the staged tile
    unsigned int tot = scr[32];
    unsigned int* dst = recs + (size_t)blockIdx.x * TILE;
    const uint4* st4 = reinterpret_cast<const uint4*>(stage);
    uint4* dst4 = reinterpret_cast<uint4*>(dst);
    if (tot == TILE) {
        // full tile: fixed trip count (3 iters), unrollable
#pragma unroll
        for (int j = 0; j < TILE / 4 / BIN_THREADS; ++j)
            dst4[j * BIN_THREADS + t] = st4[j * BIN_THREADS + t];
    } else {
        unsigned int tot4 = tot >> 2;
        for (unsigned int i = t; i < tot4; i += BIN_THREADS)
            dst4[i] = st4[i];
        for (unsigned int i = (tot4 << 2) + t; i < tot; i += BIN_THREADS)
            dst[i] = stage[i];
    }
}

// ---------------- shared decode helper ----------------
__device__ __forceinline__ float se_decode(unsigned int k,
                                           float b0, float b1, float b2,
                                           float b3, float b4) {
    unsigned c = k & 7u;
    float t = (c == 0u) ? b0 : (c == 1u) ? b1 : (c == 2u) ? b2 : (c == 3u) ? b3 : b4;
    return k ? t : 0.0f;
}

// ---------------- KC: per-bucket merge, split runs, direct bounds ----------------
__global__ __launch_bounds__(MRG_THREADS) void se_merge3(
        const unsigned int* __restrict__ startsW,   // [nblk][NPACK] u32 (u16 pairs)
        const unsigned int* __restrict__ recs,      // [nblk][TILE]
        const float* __restrict__ b,
        float* __restrict__ out,
        long long totalCells, int nblk) {
    __shared__ unsigned int tab[BCELLS];            // 64 KB
    __shared__ unsigned int eA[HMAXE];              // (tr<<16)|mid
    __shared__ unsigned int eB[HMAXE];              // en
    __shared__ unsigned int helpCnt;

    // bijective XCD swizzle: consecutive c per XCD -> adjacent runs share L2 lines
    int orig = blockIdx.x;
    int q = gridDim.x >> 3, r8 = gridDim.x & 7;
    int xcd = orig & 7, idx = orig >> 3;
    int c = (xcd < r8 ? xcd * (q + 1) : r8 * (q + 1) + (xcd - r8) * q) + idx;

    long long baseCell = (long long)c << BSHIFT;
    long long rem = totalCells - baseCell;
    int valid = rem < BCELLS ? (int)rem : BCELLS;

    int tr = threadIdx.x;
    if (tr == 0) helpCnt = 0u;

    // run bounds read directly from startsW (L2-resident 2.9MB); issue the
    // loads BEFORE the LDS zero so their latency hides under the fill loop.
    // entry c = start of bucket c; entry 2198 = segment total (scan sentinel).
    unsigned int st = 0, en = 0;
    if (tr < nblk) {
        const unsigned int* sw = startsW + (size_t)tr * NPACK;
        unsigned int w0 = sw[c >> 1];
        unsigned int w1 = sw[(c + 1) >> 1];
        st = (w0 >> ((c & 1) * 16)) & 0xFFFFu;
        en = (w1 >> (((c + 1) & 1) * 16)) & 0xFFFFu;
    }

    uint4* tab4 = reinterpret_cast<uint4*>(tab);
    for (int i = threadIdx.x; i < BCELLS / 4; i += MRG_THREADS)
        tab4[i] = make_uint4(0u, 0u, 0u, 0u);
    __syncthreads();

    // ticketing: owners of long runs hand the second half to a helper thread
    unsigned int hcap = (unsigned int)(MRG_THREADS - nblk);
    if (hcap > HMAXE) hcap = HMAXE;
    unsigned int enOwn = en;
    if (tr < nblk && (en - st) >= 8u) {
        unsigned int h = atomicAdd(&helpCnt, 1u);
        if (h < hcap) {
            unsigned int mid = (st + en) >> 1;
            eA[h] = ((unsigned int)tr << 16) | mid;
            eB[h] = en;
            enOwn = mid;
        }
    }
    __syncthreads();

    if (tr < nblk) {
        const uint4* rp4 =
            reinterpret_cast<const uint4*>(recs + (size_t)tr * TILE);
        unsigned int keyhi = (unsigned int)tr << 18;
        // aligned uint4 walk, predicated by position; out-of-range lanes
        // belong to neighbor buckets / the helper and are skipped.
        for (unsigned int i = st & ~3u; i < enOwn; i += 4) {
            uint4 r4 = rp4[i >> 2];
            if (i     >= st && i     < enOwn) atomicMax(&tab[r4.x >> 18], keyhi | (r4.x & 0x3FFFFu));
            if (i + 1 >= st && i + 1 < enOwn) atomicMax(&tab[r4.y >> 18], keyhi | (r4.y & 0x3FFFFu));
            if (i + 2 >= st && i + 2 < enOwn) atomicMax(&tab[r4.z >> 18], keyhi | (r4.z & 0x3FFFFu));
            if (i + 3 >= st && i + 3 < enOwn) atomicMax(&tab[r4.w >> 18], keyhi | (r4.w & 0x3FFFFu));
        }
    } else {
        unsigned int j = (unsigned int)(tr - nblk);
        unsigned int cnt = helpCnt;
        if (cnt > hcap) cnt = hcap;
        if (j < cnt) {
            unsigned int a = eA[j];
            unsigned int trh = a >> 16;
            unsigned int mid = a & 0xFFFFu;
            unsigned int enh = eB[j];
            const uint4* rp4 =
                reinterpret_cast<const uint4*>(recs + (size_t)trh * TILE);
            unsigned int keyhi = trh << 18;
            for (unsigned int i = mid & ~3u; i < enh; i += 4) {
                uint4 r4 = rp4[i >> 2];
                if (i     >= mid && i     < enh) atomicMax(&tab[r4.x >> 18], keyhi | (r4.x & 0x3FFFFu));
                if (i + 1 >= mid && i + 1 < enh) atomicMax(&tab[r4.y >> 18], keyhi | (r4.y & 0x3FFFFu));
                if (i + 2 >= mid && i + 2 < enh) atomicMax(&tab[r4.z >> 18], keyhi | (r4.z & 0x3FFFFu));
                if (i + 3 >= mid && i + 3 < enh) atomicMax(&tab[r4.w >> 18], keyhi | (r4.w & 0x3FFFFu));
            }
        }
    }
    __syncthreads();

    float b0 = b[0], b1 = b[1], b2 = b[2], b3 = b[3], b4 = b[4];
    float* o = out + baseCell;
    int n4 = valid >> 2;
    float4* o4 = reinterpret_cast<float4*>(o);
    for (int i = threadIdx.x; i < n4; i += MRG_THREADS) {
        uint4 k = tab4[i];
        float4 v;
        v.x = se_decode(k.x, b0, b1, b2, b3, b4);
        v.y = se_decode(k.y, b0, b1, b2, b3, b4);
        v.z = se_decode(k.z, b0, b1, b2, b3, b4);
        v.w = se_decode(k.w, b0, b1, b2, b3, b4);
        o4[i] = v;
    }
    for (int i = (n4 << 2) + threadIdx.x; i < valid; i += MRG_THREADS)
        o[i] = se_decode(tab[i], b0, b1, b2, b3, b4);
}

// ======================= FALLBACK PATH (R9, verbatim) =======================

__global__ __launch_bounds__(BIN_THREADS) void se_hist(
        const int* __restrict__ src_idx,
        const int* __restrict__ dst_idx,
        unsigned int* __restrict__ countsW,      // [nblk][NPACK] u32 (u16 pairs)
        int P, int n) {
    __shared__ unsigned int curP[NPACK];
    int t = threadIdx.x;
    for (int i = t; i < NPACK; i += BIN_THREADS) curP[i] = 0u;
    __syncthreads();

    int start = blockIdx.x * TILE;
#pragma unroll
    for (int j = 0; j < 3; ++j) {
        int base = start + j * (BIN_THREADS * 4) + t * 4;
        if (base + 3 < P) {
            int4 s = *reinterpret_cast<const int4*>(src_idx + base);
            int4 d = *reinterpret_cast<const int4*>(dst_idx + base);
            unsigned int c0 = (unsigned int)(s.x * n + d.x) >> BSHIFT;
            unsigned int c1 = (unsigned int)(s.y * n + d.y) >> BSHIFT;
            unsigned int c2 = (unsigned int)(s.z * n + d.z) >> BSHIFT;
            unsigned int c3 = (unsigned int)(s.w * n + d.w) >> BSHIFT;
            atomicAdd(&curP[c0 >> 1], (c0 & 1) ? 0x10000u : 1u);
            atomicAdd(&curP[c1 >> 1], (c1 & 1) ? 0x10000u : 1u);
            atomicAdd(&curP[c2 >> 1], (c2 & 1) ? 0x10000u : 1u);
            atomicAdd(&curP[c3 >> 1], (c3 & 1) ? 0x10000u : 1u);
        } else {
            for (int p = base; p < P && p < base + 4; ++p) {
                unsigned int c = (unsigned int)(src_idx[p] * n + dst_idx[p]) >> BSHIFT;
                atomicAdd(&curP[c >> 1], (c & 1) ? 0x10000u : 1u);
            }
        }
    }
    __syncthreads();
    for (int i = t; i < NPACK; i += BIN_THREADS)
        countsW[(size_t)blockIdx.x * NPACK + i] = curP[i];
}

__global__ __launch_bounds__(256) void se_scan(
        unsigned int* __restrict__ countsW,   // in: counts, out: bases (in place)
        unsigned short* __restrict__ basesT,  // [NBUCK][nblk+1] u16, sentinel=total
        int nblk) {
    __shared__ unsigned short lds16[MAXBLK * SCAN_TB];   // 21 KB
    unsigned int* lds32 = reinterpret_cast<unsigned int*>(lds16);
    int t = threadIdx.x;
    int c0 = blockIdx.x * SCAN_TB;
    int w0 = c0 >> 1;
    int words = nblk * (SCAN_TB / 2);

    for (int i = t; i < words; i += 256) {
        int r = i >> 3, w = i & 7;
        if (w0 + w < NPACK)
            lds32[r * 8 + w] = countsW[(size_t)r * NPACK + w0 + w];
    }
    __syncthreads();

    if (t < SCAN_TB && c0 + t < NBUCK) {
        unsigned int acc = 0;
        for (int r = 0; r < nblk; ++r) {
            unsigned short v = lds16[r * SCAN_TB + t];
            lds16[r * SCAN_TB + t] = (unsigned short)acc;
            acc += v;
        }
        basesT[(size_t)(c0 + t) * (nblk + 1) + nblk] = (unsigned short)acc;
    }
    __syncthreads();

    for (int i = t; i < words; i += 256) {
        int r = i >> 3, w = i & 7;
        if (w0 + w < NPACK)
            countsW[(size_t)r * NPACK + w0 + w] = lds32[r * 8 + w];
    }
    for (int k = 0; k < SCAN_TB; ++k) {
        int c = c0 + k;
        if (c >= NBUCK) break;
        for (int r = t; r < nblk; r += 256)
            basesT[(size_t)c * (nblk + 1) + r] = lds16[r * SCAN_TB + k];
    }
}

__global__ __launch_bounds__(BIN_THREADS) void se_bin5(
        const int* __restrict__ src_idx,
        const int* __restrict__ dst_idx,
        const int* __restrict__ path_len,
        unsigned int* __restrict__ recs,         // d_out viewed as u32
        const unsigned int* __restrict__ basesW, // countsW after scan (u16 pairs)
        int P, int n) {
    __shared__ unsigned int histP[NPACK];
    __shared__ unsigned int curP[NPACK];
    __shared__ unsigned int gbaseP[NPACK];
    __shared__ unsigned int stage[TILE];
    __shared__ unsigned int scr[34];

    int t = threadIdx.x;
    int start = blockIdx.x * TILE;

    for (int i = t; i < NPACK; i += BIN_THREADS) curP[i] = 0u;
    __syncthreads();

    int cells[12];
    unsigned int lows[12];
#pragma unroll
    for (int j = 0; j < 3; ++j) {
        int base = start + j * (BIN_THREADS * 4) + t * 4;
        int k0 = j * 4;
        if (base + 3 < P) {
            int4 s = *reinterpret_cast<const int4*>(src_idx + base);
            int4 d = *reinterpret_cast<const int4*>(dst_idx + base);
            int4 l = *reinterpret_cast<const int4*>(path_len + base);
            int lp = base - start;
            cells[k0]     = s.x * n + d.x;
            cells[k0 + 1] = s.y * n + d.y;
            cells[k0 + 2] = s.z * n + d.z;
            cells[k0 + 3] = s.w * n + d.w;
            lows[k0]     = ((unsigned int)(lp + 1) << 3) | (unsigned int)((l.x < 5 ? l.x : 5) - 1);
            lows[k0 + 1] = ((unsigned int)(lp + 2) << 3) | (unsigned int)((l.y < 5 ? l.y : 5) - 1);
            lows[k0 + 2] = ((unsigned int)(lp + 3) << 3) | (unsigned int)((l.z < 5 ? l.z : 5) - 1);
            lows[k0 + 3] = ((unsigned int)(lp + 4) << 3) | (unsigned int)((l.w < 5 ? l.w : 5) - 1);
        } else {
#pragma unroll
            for (int jj = 0; jj < 4; ++jj) {
                int p = base + jj;
                if (p < P) {
                    cells[k0 + jj] = src_idx[p] * n + dst_idx[p];
                    int len = path_len[p];
                    int cl = (len < 5 ? len : 5) - 1;
                    lows[k0 + jj] = ((unsigned int)(p - start + 1) << 3) | (unsigned int)cl;
                } else {
                    cells[k0 + jj] = -1;
                    lows[k0 + jj] = 0u;
                }
            }
        }
    }
#pragma unroll
    for (int k = 0; k < 12; ++k) {
        if (cells[k] >= 0) {
            unsigned int c = (unsigned int)cells[k] >> BSHIFT;
            atomicAdd(&curP[c >> 1], (c & 1) ? 0x10000u : 1u);
        }
    }
    __syncthreads();

    unsigned int l0 = 0, l1 = 0, l2v = 0, l3 = 0, s = 0;
    if (t < NOWN) {
        unsigned int w0 = curP[2 * t], w1 = curP[2 * t + 1];
        unsigned int v0 = w0 & 0xFFFFu, v1 = w0 >> 16;
        unsigned int v2 = w1 & 0xFFFFu, v3 = w1 >> 16;
        l0 = 0; l1 = v0; l2v = v0 + v1; l3 = v0 + v1 + v2;
        s = v0 + v1 + v2 + v3;
    }
    unsigned int x = s;
    for (int d = 1; d < 64; d <<= 1) {
        unsigned int y = (unsigned int)__shfl_up((int)x, d, 64);
        if ((t & 63) >= d) x += y;
    }
    if ((t & 63) == 63) scr[t >> 6] = x;
    __syncthreads();
    if (t == 0) {
        unsigned int acc = 0;
        for (int w = 0; w < 16; ++w) { unsigned int v = scr[w]; scr[16 + w] = acc; acc += v; }
        scr[32] = acc;
    }
    __syncthreads();
    unsigned int exc = x - s + scr[16 + (t >> 6)];
    if (t < NOWN) {
        unsigned int st0 = exc + l0, st1 = exc + l1, st2 = exc + l2v, st3 = exc + l3;
        histP[2 * t]     = (st0 & 0xFFFFu) | (st1 << 16);
        histP[2 * t + 1] = (st2 & 0xFFFFu) | (st3 << 16);
    }
    __syncthreads();

    for (int i = t; i < NPACK; i += BIN_THREADS) {
        gbaseP[i] = basesW[(size_t)blockIdx.x * NPACK + i];
        curP[i] = histP[i];
    }
    __syncthreads();

#pragma unroll
    for (int k = 0; k < 12; ++k) {
        if (cells[k] >= 0) {
            unsigned int cell = (unsigned int)cells[k];
            unsigned int c = cell >> BSHIFT;
            unsigned int old = atomicAdd(&curP[c >> 1], (c & 1) ? 0x10000u : 1u);
            unsigned int pos = (old >> ((c & 1) * 16)) & 0xFFFFu;
            stage[pos] = ((cell & (BCELLS - 1)) << 18) | lows[k];
        }
    }
    __syncthreads();

    unsigned int tot = scr[32];
    for (unsigned int i = t; i < tot; i += BIN_THREADS) {
        unsigned int rec = stage[i];
        unsigned int lo = 0, hi = 2199;
        while (lo < hi) {
            unsigned int mid = (lo + hi + 1) >> 1;
            if (unpack16(histP, mid) <= i) lo = mid; else hi = mid - 1;
        }
        unsigned int c = lo;
        unsigned int pos = unpack16(gbaseP, c) + (i - unpack16(histP, c));
        recs[(size_t)c * BCELLS + pos] = rec;
    }
}

__global__ __launch_bounds__(MRG_THREADS) void se_merge(
        const unsigned short* __restrict__ basesT,  // [NBUCK][nblk+1]
        const float* __restrict__ b,
        float* __restrict__ out,              // same memory as recs
        long long totalCells, int nblk) {
    __shared__ unsigned int tab[BCELLS];

    int c = blockIdx.x;
    long long baseCell = (long long)c << BSHIFT;
    long long rem = totalCells - baseCell;
    int valid = rem < BCELLS ? (int)rem : BCELLS;

    uint4* tab4 = reinterpret_cast<uint4*>(tab);
    for (int i = threadIdx.x; i < BCELLS / 4; i += MRG_THREADS)
        tab4[i] = make_uint4(0u, 0u, 0u, 0u);
    __syncthreads();

    const unsigned int* r =
        reinterpret_cast<const unsigned int*>(out) + (size_t)c * BCELLS;
    int tr = threadIdx.x;
    if (tr < nblk) {
        const unsigned short* B = basesT + (size_t)c * (nblk + 1);
        unsigned int rb0 = B[tr], rb1 = B[tr + 1];
        unsigned int keyhi = (unsigned int)tr << 18;
        for (unsigned int i = rb0; i < rb1; ++i) {
            unsigned int rec = r[i];
            atomicMax(&tab[rec >> 18], keyhi | (rec & 0x3FFFFu));
        }
    }
    __syncthreads();

    float b0 = b[0], b1 = b[1], b2 = b[2], b3 = b[3], b4 = b[4];
    float* o = out + baseCell;
    int n4 = valid >> 2;
    float4* o4 = reinterpret_cast<float4*>(o);
    for (int i = threadIdx.x; i < n4; i += MRG_THREADS) {
        uint4 k = tab4[i];
        float4 v;
        v.x = se_decode(k.x, b0, b1, b2, b3, b4);
        v.y = se_decode(k.y, b0, b1, b2, b3, b4);
        v.z = se_decode(k.z, b0, b1, b2, b3, b4);
        v.w = se_decode(k.w, b0, b1, b2, b3, b4);
        o4[i] = v;
    }
    for (int i = (n4 << 2) + threadIdx.x; i < valid; i += MRG_THREADS)
        o[i] = se_decode(tab[i], b0, b1, b2, b3, b4);
}

// ======================= launch =======================

extern "C" void kernel_launch(void* const* d_in, const int* in_sizes, int n_in,
                              void* d_out, int out_size, void* d_ws, size_t ws_size,
                              hipStream_t stream) {
    // inputs: 0=x [N*128 f32], 1=b [5 f32], 2=src_idx [P i32], 3=dst_idx [P i32], 4=path_len [P i32]
    const float* b        = (const float*)d_in[1];
    const int*   src_idx  = (const int*)d_in[2];
    const int*   dst_idx  = (const int*)d_in[3];
    const int*   path_len = (const int*)d_in[4];
    int P = in_sizes[2];
    int n = in_sizes[0] / 128;                      // N = 6000
    long long totalCells = (long long)n * n;        // 36,000,000
    int nblk = (P + TILE - 1) / TILE;               // 652

    // Fast path ws layout: recs [nblk*TILE u32] (32.1 MB) |
    //                      startsW [nblk*NPACK u32] (2.9 MB)
    size_t needFast = (size_t)nblk * TILE * 4u
                    + (size_t)nblk * NPACK * 4u;

    if (ws_size >= needFast && nblk <= MRG_THREADS) {
        unsigned int* recs    = (unsigned int*)d_ws;
        unsigned int* startsW = recs + (size_t)nblk * TILE;

        se_bin_local<<<nblk, BIN_THREADS, 0, stream>>>(
            src_idx, dst_idx, path_len, recs, startsW, P, n);

        se_merge3<<<NBUCK, MRG_THREADS, 0, stream>>>(
            startsW, recs, b, (float*)d_out, totalCells, nblk);
    } else {
        // R9 fallback: records staged in d_out at global per-bucket bases
        unsigned int*   countsW = (unsigned int*)d_ws;
        unsigned short* basesT  = (unsigned short*)(countsW + (size_t)nblk * NPACK);

        se_hist<<<nblk, BIN_THREADS, 0, stream>>>(src_idx, dst_idx, countsW, P, n);
        se_scan<<<(NBUCK + SCAN_TB - 1) / SCAN_TB, 256, 0, stream>>>(countsW, basesT, nblk);
        se_bin5<<<nblk, BIN_THREADS, 0, stream>>>(
            src_idx, dst_idx, path_len, (unsigned int*)d_out, countsW, P, n);
        se_merge<<<NBUCK, MRG_THREADS, 0, stream>>>(basesT, b, (float*)d_out,
                                                    totalCells, nblk);
    }
}

// Round 5
// 257.642 us; speedup vs baseline: 1.0211x; 1.0206x over previous
//
#include <hip/hip_runtime.h>

// SpatialEncoding: out[src,dst] = b[min(path_len,5)-1], last-write-wins in p order.
//
// R14: occupancy fix -- force 2 blocks/CU on both big kernels.
//   Theory: bin/merge were at 1 block/CU (VGPR>64 at 1024 thr => only 16
//   waves/CU) making them latency-bound; explains R12/R13 nulls and R11's
//   -18us from fewer serialized VMEM rounds.
//   KA se_bin_local : __launch_bounds__(1024,8) (VGPR<=64). Live state cut
//                     24->18 regs: cc[12] = (cell<<3)|clamped (29 bits),
//                     ranks packed 2/u32 in rk[6], local_p recomputed from
//                     (k,t) at store time. Single-atomic counting sort
//                     (rank from histogram atomicAdd), pure-store placement,
//                     linear b128 flush.
//   KC se_merge3    : __launch_bounds__(1024,8). Run bounds read directly
//                     from startsW (L2-resident) BEFORE the LDS zero; simple
//                     predicated uint4 walk (R11); tickets dropped (null).
//                     Bijective XCD swizzle on c.
//   Fallback path (small ws): R9 pipeline verbatim.
//
//   rec(u32) = off(14 bits [31:18]) | (local_p+1)(15 bits [17:3]) | clamped(3)
//   merge key = (blk_rank(10) << 18) | (rec & 0x3FFFF)  (28 bits, >0 always)

#define BSHIFT 14
#define BCELLS (1 << BSHIFT)            // 16384 cells per bucket (64 KB region)
#define NBUCK  2198                     // ceil(36e6 / 16384)
#define NPACK  1100                     // ceil(NBUCK/2)+pad (in-bounds for owners)
#define NOWN   550                      // owner threads, 4 buckets each
#define BIN_THREADS 1024
#define TILE   12288                    // pairs per bin block
#define SCAN_TB 16                      // buckets per scan block (fallback)
#define MAXBLK 656                      // >= ceil(8e6/12288)=652
#define MRG_THREADS 1024

__device__ __forceinline__ unsigned int unpack16(const unsigned int* A, unsigned int c) {
    return (A[c >> 1] >> ((c & 1) * 16)) & 0xFFFFu;
}

// ======================= FAST PATH =======================

// ---------------- KA: single-pass local binning (VGPR-lean) ----------------
__global__ __launch_bounds__(BIN_THREADS, 8) void se_bin_local(
        const int* __restrict__ src_idx,
        const int* __restrict__ dst_idx,
        const int* __restrict__ path_len,
        unsigned int* __restrict__ recs,        // ws: [nblk][TILE] u32
        unsigned int* __restrict__ startsW,     // ws: [nblk][NPACK] u32 (u16 pairs)
        int P, int n) {
    __shared__ unsigned int histP[NPACK];       // local run starts (packed u16)
    __shared__ unsigned int curP[NPACK];        // counts
    __shared__ unsigned int stage[TILE];        // 48 KB u32 staging
    __shared__ unsigned int scr[34];

    int t = threadIdx.x;
    int start = blockIdx.x * TILE;

    for (int i = t; i < NPACK; i += BIN_THREADS) curP[i] = 0u;
    __syncthreads();

    // Phase A: read 12 pairs/thread (int4 x3).
    // cc[k] = (cell << 3) | clamped  (29 bits; 0xFFFFFFFF = invalid slot)
    unsigned int cc[12];
    unsigned int rk[6];                         // ranks packed 2 per u32
#pragma unroll
    for (int j = 0; j < 3; ++j) {
        int base = start + j * (BIN_THREADS * 4) + t * 4;
        int k0 = j * 4;
        if (base + 3 < P) {
            int4 s = *reinterpret_cast<const int4*>(src_idx + base);
            int4 d = *reinterpret_cast<const int4*>(dst_idx + base);
            int4 l = *reinterpret_cast<const int4*>(path_len + base);
            cc[k0]     = ((unsigned int)(s.x * n + d.x) << 3) | (unsigned int)((l.x < 5 ? l.x : 5) - 1);
            cc[k0 + 1] = ((unsigned int)(s.y * n + d.y) << 3) | (unsigned int)((l.y < 5 ? l.y : 5) - 1);
            cc[k0 + 2] = ((unsigned int)(s.z * n + d.z) << 3) | (unsigned int)((l.z < 5 ? l.z : 5) - 1);
            cc[k0 + 3] = ((unsigned int)(s.w * n + d.w) << 3) | (unsigned int)((l.w < 5 ? l.w : 5) - 1);
        } else {
#pragma unroll
            for (int jj = 0; jj < 4; ++jj) {
                int p = base + jj;
                if (p < P) {
                    int len = path_len[p];
                    cc[k0 + jj] = ((unsigned int)(src_idx[p] * n + dst_idx[p]) << 3)
                                | (unsigned int)((len < 5 ? len : 5) - 1);
                } else {
                    cc[k0 + jj] = 0xFFFFFFFFu;
                }
            }
        }
    }
    // Histogram: atomicAdd return value = within-bucket rank (< TILE < 2^16)
#pragma unroll
    for (int k = 0; k < 12; ++k) {
        unsigned int r = 0;
        if (cc[k] != 0xFFFFFFFFu) {
            unsigned int c = cc[k] >> 17;       // bucket = cell >> 14
            unsigned int old = atomicAdd(&curP[c >> 1], (c & 1) ? 0x10000u : 1u);
            r = (old >> ((c & 1) * 16)) & 0xFFFFu;
        }
        if (k & 1) rk[k >> 1] |= r << 16; else rk[k >> 1] = r;
    }
    __syncthreads();

    // Phase B: block-wide exclusive scan of counts -> local run starts (histP)
    unsigned int l0 = 0, l1 = 0, l2v = 0, l3 = 0, s = 0;
    if (t < NOWN) {
        unsigned int w0 = curP[2 * t], w1 = curP[2 * t + 1];
        unsigned int v0 = w0 & 0xFFFFu, v1 = w0 >> 16;
        unsigned int v2 = w1 & 0xFFFFu, v3 = w1 >> 16;
        l0 = 0; l1 = v0; l2v = v0 + v1; l3 = v0 + v1 + v2;
        s = v0 + v1 + v2 + v3;
    }
    unsigned int x = s;
    for (int d = 1; d < 64; d <<= 1) {
        unsigned int y = (unsigned int)__shfl_up((int)x, d, 64);
        if ((t & 63) >= d) x += y;
    }
    if ((t & 63) == 63) scr[t >> 6] = x;
    __syncthreads();
    if (t == 0) {
        unsigned int acc = 0;
        for (int w = 0; w < 16; ++w) { unsigned int v = scr[w]; scr[16 + w] = acc; acc += v; }
        scr[32] = acc;
    }
    __syncthreads();
    unsigned int exc = x - s + scr[16 + (t >> 6)];
    if (t < NOWN) {
        unsigned int st0 = exc + l0, st1 = exc + l1, st2 = exc + l2v, st3 = exc + l3;
        histP[2 * t]     = (st0 & 0xFFFFu) | (st1 << 16);
        histP[2 * t + 1] = (st2 & 0xFFFFu) | (st3 << 16);
    }
    __syncthreads();

    // Phase C': persist local starts (coalesced)
    for (int i = t; i < NPACK; i += BIN_THREADS)
        startsW[(size_t)blockIdx.x * NPACK + i] = histP[i];

    // Phase D': place records -- PURE stores at start[bucket] + rank;
    // local_p recomputed from (k, t), clamped taken from cc low bits.
#pragma unroll
    for (int k = 0; k < 12; ++k) {
        if (cc[k] != 0xFFFFFFFFu) {
            unsigned int c = cc[k] >> 17;
            unsigned int rank = (rk[k >> 1] >> ((k & 1) * 16)) & 0xFFFFu;
            unsigned int pos = unpack16(histP, c) + rank;
            unsigned int lp1 = (unsigned int)((k >> 2) * (BIN_THREADS * 4) + t * 4 + (k & 3) + 1);
            stage[pos] = (((cc[k] >> 3) & (BCELLS - 1)) << 18) | (lp1 << 3) | (cc[k] & 7u);
        }
    }
    __syncthreads();

    // Phase E': LINEAR coalesced b128 flush of the staged tile
    unsigned int tot = scr[32];
    unsigned int* dst = recs + (size_t)blockIdx.x * TILE;
    const uint4* st4 = reinterpret_cast<const uint4*>(stage);
    uint4* dst4 = reinterpret_cast<uint4*>(dst);
    if (tot == TILE) {
#pragma unroll
        for (int j = 0; j < TILE / 4 / BIN_THREADS; ++j)
            dst4[j * BIN_THREADS + t] = st4[j * BIN_THREADS + t];
    } else {
        unsigned int tot4 = tot >> 2;
        for (unsigned int i = t; i < tot4; i += BIN_THREADS)
            dst4[i] = st4[i];
        for (unsigned int i = (tot4 << 2) + t; i < tot; i += BIN_THREADS)
            dst[i] = stage[i];
    }
}

// ---------------- shared decode helper ----------------
__device__ __forceinline__ float se_decode(unsigned int k,
                                           float b0, float b1, float b2,
                                           float b3, float b4) {
    unsigned c = k & 7u;
    float t = (c == 0u) ? b0 : (c == 1u) ? b1 : (c == 2u) ? b2 : (c == 3u) ? b3 : b4;
    return k ? t : 0.0f;
}

// ---------------- KC: per-bucket merge, direct bounds, uint4 walk ----------------
__global__ __launch_bounds__(MRG_THREADS, 8) void se_merge3(
        const unsigned int* __restrict__ startsW,   // [nblk][NPACK] u32 (u16 pairs)
        const unsigned int* __restrict__ recs,      // [nblk][TILE]
        const float* __restrict__ b,
        float* __restrict__ out,
        long long totalCells, int nblk) {
    __shared__ unsigned int tab[BCELLS];            // 64 KB

    // bijective XCD swizzle: consecutive c per XCD -> adjacent runs share L2 lines
    int orig = blockIdx.x;
    int q = gridDim.x >> 3, r8 = gridDim.x & 7;
    int xcd = orig & 7, idx = orig >> 3;
    int c = (xcd < r8 ? xcd * (q + 1) : r8 * (q + 1) + (xcd - r8) * q) + idx;

    long long baseCell = (long long)c << BSHIFT;
    long long rem = totalCells - baseCell;
    int valid = rem < BCELLS ? (int)rem : BCELLS;

    // run bounds read directly from startsW (L2-resident 2.9MB); issued
    // BEFORE the LDS zero so their latency hides under the fill loop.
    // entry c = start of bucket c; entry 2198 = segment total (scan covers
    // buckets 0..2199, 2198/2199 always empty -> entry 2198 == total).
    int tr = threadIdx.x;
    unsigned int st = 0, en = 0;
    if (tr < nblk) {
        const unsigned int* sw = startsW + (size_t)tr * NPACK;
        unsigned int w0 = sw[c >> 1];
        unsigned int w1 = sw[(c + 1) >> 1];
        st = (w0 >> ((c & 1) * 16)) & 0xFFFFu;
        en = (w1 >> (((c + 1) & 1) * 16)) & 0xFFFFu;
    }

    uint4* tab4 = reinterpret_cast<uint4*>(tab);
    for (int i = threadIdx.x; i < BCELLS / 4; i += MRG_THREADS)
        tab4[i] = make_uint4(0u, 0u, 0u, 0u);
    __syncthreads();

    if (tr < nblk) {
        const uint4* rp4 =
            reinterpret_cast<const uint4*>(recs + (size_t)tr * TILE);
        unsigned int keyhi = (unsigned int)tr << 18;
        // aligned uint4 walk, predicated by position; out-of-run lanes belong
        // to neighbor buckets and are skipped. i+3 <= TILE-1 always (TILE%4==0).
        for (unsigned int i = st & ~3u; i < en; i += 4) {
            uint4 r4 = rp4[i >> 2];
            if (i     >= st && i     < en) atomicMax(&tab[r4.x >> 18], keyhi | (r4.x & 0x3FFFFu));
            if (i + 1 >= st && i + 1 < en) atomicMax(&tab[r4.y >> 18], keyhi | (r4.y & 0x3FFFFu));
            if (i + 2 >= st && i + 2 < en) atomicMax(&tab[r4.z >> 18], keyhi | (r4.z & 0x3FFFFu));
            if (i + 3 >= st && i + 3 < en) atomicMax(&tab[r4.w >> 18], keyhi | (r4.w & 0x3FFFFu));
        }
    }
    __syncthreads();

    float b0 = b[0], b1 = b[1], b2 = b[2], b3 = b[3], b4 = b[4];
    float* o = out + baseCell;
    int n4 = valid >> 2;
    float4* o4 = reinterpret_cast<float4*>(o);
    for (int i = threadIdx.x; i < n4; i += MRG_THREADS) {
        uint4 k = tab4[i];
        float4 v;
        v.x = se_decode(k.x, b0, b1, b2, b3, b4);
        v.y = se_decode(k.y, b0, b1, b2, b3, b4);
        v.z = se_decode(k.z, b0, b1, b2, b3, b4);
        v.w = se_decode(k.w, b0, b1, b2, b3, b4);
        o4[i] = v;
    }
    for (int i = (n4 << 2) + threadIdx.x; i < valid; i += MRG_THREADS)
        o[i] = se_decode(tab[i], b0, b1, b2, b3, b4);
}

// ======================= FALLBACK PATH (R9, verbatim) =======================

__global__ __launch_bounds__(BIN_THREADS) void se_hist(
        const int* __restrict__ src_idx,
        const int* __restrict__ dst_idx,
        unsigned int* __restrict__ countsW,      // [nblk][NPACK] u32 (u16 pairs)
        int P, int n) {
    __shared__ unsigned int curP[NPACK];
    int t = threadIdx.x;
    for (int i = t; i < NPACK; i += BIN_THREADS) curP[i] = 0u;
    __syncthreads();

    int start = blockIdx.x * TILE;
#pragma unroll
    for (int j = 0; j < 3; ++j) {
        int base = start + j * (BIN_THREADS * 4) + t * 4;
        if (base + 3 < P) {
            int4 s = *reinterpret_cast<const int4*>(src_idx + base);
            int4 d = *reinterpret_cast<const int4*>(dst_idx + base);
            unsigned int c0 = (unsigned int)(s.x * n + d.x) >> BSHIFT;
            unsigned int c1 = (unsigned int)(s.y * n + d.y) >> BSHIFT;
            unsigned int c2 = (unsigned int)(s.z * n + d.z) >> BSHIFT;
            unsigned int c3 = (unsigned int)(s.w * n + d.w) >> BSHIFT;
            atomicAdd(&curP[c0 >> 1], (c0 & 1) ? 0x10000u : 1u);
            atomicAdd(&curP[c1 >> 1], (c1 & 1) ? 0x10000u : 1u);
            atomicAdd(&curP[c2 >> 1], (c2 & 1) ? 0x10000u : 1u);
            atomicAdd(&curP[c3 >> 1], (c3 & 1) ? 0x10000u : 1u);
        } else {
            for (int p = base; p < P && p < base + 4; ++p) {
                unsigned int c = (unsigned int)(src_idx[p] * n + dst_idx[p]) >> BSHIFT;
                atomicAdd(&curP[c >> 1], (c & 1) ? 0x10000u : 1u);
            }
        }
    }
    __syncthreads();
    for (int i = t; i < NPACK; i += BIN_THREADS)
        countsW[(size_t)blockIdx.x * NPACK + i] = curP[i];
}

__global__ __launch_bounds__(256) void se_scan(
        unsigned int* __restrict__ countsW,   // in: counts, out: bases (in place)
        unsigned short* __restrict__ basesT,  // [NBUCK][nblk+1] u16, sentinel=total
        int nblk) {
    __shared__ unsigned short lds16[MAXBLK * SCAN_TB];   // 21 KB
    unsigned int* lds32 = reinterpret_cast<unsigned int*>(lds16);
    int t = threadIdx.x;
    int c0 = blockIdx.x * SCAN_TB;
    int w0 = c0 >> 1;
    int words = nblk * (SCAN_TB / 2);

    for (int i = t; i < words; i += 256) {
        int r = i >> 3, w = i & 7;
        if (w0 + w < NPACK)
            lds32[r * 8 + w] = countsW[(size_t)r * NPACK + w0 + w];
    }
    __syncthreads();

    if (t < SCAN_TB && c0 + t < NBUCK) {
        unsigned int acc = 0;
        for (int r = 0; r < nblk; ++r) {
            unsigned short v = lds16[r * SCAN_TB + t];
            lds16[r * SCAN_TB + t] = (unsigned short)acc;
            acc += v;
        }
        basesT[(size_t)(c0 + t) * (nblk + 1) + nblk] = (unsigned short)acc;
    }
    __syncthreads();

    for (int i = t; i < words; i += 256) {
        int r = i >> 3, w = i & 7;
        if (w0 + w < NPACK)
            countsW[(size_t)r * NPACK + w0 + w] = lds32[r * 8 + w];
    }
    for (int k = 0; k < SCAN_TB; ++k) {
        int c = c0 + k;
        if (c >= NBUCK) break;
        for (int r = t; r < nblk; r += 256)
            basesT[(size_t)c * (nblk + 1) + r] = lds16[r * SCAN_TB + k];
    }
}

__global__ __launch_bounds__(BIN_THREADS) void se_bin5(
        const int* __restrict__ src_idx,
        const int* __restrict__ dst_idx,
        const int* __restrict__ path_len,
        unsigned int* __restrict__ recs,         // d_out viewed as u32
        const unsigned int* __restrict__ basesW, // countsW after scan (u16 pairs)
        int P, int n) {
    __shared__ unsigned int histP[NPACK];
    __shared__ unsigned int curP[NPACK];
    __shared__ unsigned int gbaseP[NPACK];
    __shared__ unsigned int stage[TILE];
    __shared__ unsigned int scr[34];

    int t = threadIdx.x;
    int start = blockIdx.x * TILE;

    for (int i = t; i < NPACK; i += BIN_THREADS) curP[i] = 0u;
    __syncthreads();

    int cells[12];
    unsigned int lows[12];
#pragma unroll
    for (int j = 0; j < 3; ++j) {
        int base = start + j * (BIN_THREADS * 4) + t * 4;
        int k0 = j * 4;
        if (base + 3 < P) {
            int4 s = *reinterpret_cast<const int4*>(src_idx + base);
            int4 d = *reinterpret_cast<const int4*>(dst_idx + base);
            int4 l = *reinterpret_cast<const int4*>(path_len + base);
            int lp = base - start;
            cells[k0]     = s.x * n + d.x;
            cells[k0 + 1] = s.y * n + d.y;
            cells[k0 + 2] = s.z * n + d.z;
            cells[k0 + 3] = s.w * n + d.w;
            lows[k0]     = ((unsigned int)(lp + 1) << 3) | (unsigned int)((l.x < 5 ? l.x : 5) - 1);
            lows[k0 + 1] = ((unsigned int)(lp + 2) << 3) | (unsigned int)((l.y < 5 ? l.y : 5) - 1);
            lows[k0 + 2] = ((unsigned int)(lp + 3) << 3) | (unsigned int)((l.z < 5 ? l.z : 5) - 1);
            lows[k0 + 3] = ((unsigned int)(lp + 4) << 3) | (unsigned int)((l.w < 5 ? l.w : 5) - 1);
        } else {
#pragma unroll
            for (int jj = 0; jj < 4; ++jj) {
                int p = base + jj;
                if (p < P) {
                    cells[k0 + jj] = src_idx[p] * n + dst_idx[p];
                    int len = path_len[p];
                    int cl = (len < 5 ? len : 5) - 1;
                    lows[k0 + jj] = ((unsigned int)(p - start + 1) << 3) | (unsigned int)cl;
                } else {
                    cells[k0 + jj] = -1;
                    lows[k0 + jj] = 0u;
                }
            }
        }
    }
#pragma unroll
    for (int k = 0; k < 12; ++k) {
        if (cells[k] >= 0) {
            unsigned int c = (unsigned int)cells[k] >> BSHIFT;
            atomicAdd(&curP[c >> 1], (c & 1) ? 0x10000u : 1u);
        }
    }
    __syncthreads();

    unsigned int l0 = 0, l1 = 0, l2v = 0, l3 = 0, s = 0;
    if (t < NOWN) {
        unsigned int w0 = curP[2 * t], w1 = curP[2 * t + 1];
        unsigned int v0 = w0 & 0xFFFFu, v1 = w0 >> 16;
        unsigned int v2 = w1 & 0xFFFFu, v3 = w1 >> 16;
        l0 = 0; l1 = v0; l2v = v0 + v1; l3 = v0 + v1 + v2;
        s = v0 + v1 + v2 + v3;
    }
    unsigned int x = s;
    for (int d = 1; d < 64; d <<= 1) {
        unsigned int y = (unsigned int)__shfl_up((int)x, d, 64);
        if ((t & 63) >= d) x += y;
    }
    if ((t & 63) == 63) scr[t >> 6] = x;
    __syncthreads();
    if (t == 0) {
        unsigned int acc = 0;
        for (int w = 0; w < 16; ++w) { unsigned int v = scr[w]; scr[16 + w] = acc; acc += v; }
        scr[32] = acc;
    }
    __syncthreads();
    unsigned int exc = x - s + scr[16 + (t >> 6)];
    if (t < NOWN) {
        unsigned int st0 = exc + l0, st1 = exc + l1, st2 = exc + l2v, st3 = exc + l3;
        histP[2 * t]     = (st0 & 0xFFFFu) | (st1 << 16);
        histP[2 * t + 1] = (st2 & 0xFFFFu) | (st3 << 16);
    }
    __syncthreads();

    for (int i = t; i < NPACK; i += BIN_THREADS) {
        gbaseP[i] = basesW[(size_t)blockIdx.x * NPACK + i];
        curP[i] = histP[i];
    }
    __syncthreads();

#pragma unroll
    for (int k = 0; k < 12; ++k) {
        if (cells[k] >= 0) {
            unsigned int cell = (unsigned int)cells[k];
            unsigned int c = cell >> BSHIFT;
            unsigned int old = atomicAdd(&curP[c >> 1], (c & 1) ? 0x10000u : 1u);
            unsigned int pos = (old >> ((c & 1) * 16)) & 0xFFFFu;
            stage[pos] = ((cell & (BCELLS - 1)) << 18) | lows[k];
        }
    }
    __syncthreads();

    unsigned int tot = scr[32];
    for (unsigned int i = t; i < tot; i += BIN_THREADS) {
        unsigned int rec = stage[i];
        unsigned int lo = 0, hi = 2199;
        while (lo < hi) {
            unsigned int mid = (lo + hi + 1) >> 1;
            if (unpack16(histP, mid) <= i) lo = mid; else hi = mid - 1;
        }
        unsigned int c = lo;
        unsigned int pos = unpack16(gbaseP, c) + (i - unpack16(histP, c));
        recs[(size_t)c * BCELLS + pos] = rec;
    }
}

__global__ __launch_bounds__(MRG_THREADS) void se_merge(
        const unsigned short* __restrict__ basesT,  // [NBUCK][nblk+1]
        const float* __restrict__ b,
        float* __restrict__ out,              // same memory as recs
        long long totalCells, int nblk) {
    __shared__ unsigned int tab[BCELLS];

    int c = blockIdx.x;
    long long baseCell = (long long)c << BSHIFT;
    long long rem = totalCells - baseCell;
    int valid = rem < BCELLS ? (int)rem : BCELLS;

    uint4* tab4 = reinterpret_cast<uint4*>(tab);
    for (int i = threadIdx.x; i < BCELLS / 4; i += MRG_THREADS)
        tab4[i] = make_uint4(0u, 0u, 0u, 0u);
    __syncthreads();

    const unsigned int* r =
        reinterpret_cast<const unsigned int*>(out) + (size_t)c * BCELLS;
    int tr = threadIdx.x;
    if (tr < nblk) {
        const unsigned short* B = basesT + (size_t)c * (nblk + 1);
        unsigned int rb0 = B[tr], rb1 = B[tr + 1];
        unsigned int keyhi = (unsigned int)tr << 18;
        for (unsigned int i = rb0; i < rb1; ++i) {
            unsigned int rec = r[i];
            atomicMax(&tab[rec >> 18], keyhi | (rec & 0x3FFFFu));
        }
    }
    __syncthreads();

    float b0 = b[0], b1 = b[1], b2 = b[2], b3 = b[3], b4 = b[4];
    float* o = out + baseCell;
    int n4 = valid >> 2;
    float4* o4 = reinterpret_cast<float4*>(o);
    for (int i = threadIdx.x; i < n4; i += MRG_THREADS) {
        uint4 k = tab4[i];
        float4 v;
        v.x = se_decode(k.x, b0, b1, b2, b3, b4);
        v.y = se_decode(k.y, b0, b1, b2, b3, b4);
        v.z = se_decode(k.z, b0, b1, b2, b3, b4);
        v.w = se_decode(k.w, b0, b1, b2, b3, b4);
        o4[i] = v;
    }
    for (int i = (n4 << 2) + threadIdx.x; i < valid; i += MRG_THREADS)
        o[i] = se_decode(tab[i], b0, b1, b2, b3, b4);
}

// ======================= launch =======================

extern "C" void kernel_launch(void* const* d_in, const int* in_sizes, int n_in,
                              void* d_out, int out_size, void* d_ws, size_t ws_size,
                              hipStream_t stream) {
    // inputs: 0=x [N*128 f32], 1=b [5 f32], 2=src_idx [P i32], 3=dst_idx [P i32], 4=path_len [P i32]
    const float* b        = (const float*)d_in[1];
    const int*   src_idx  = (const int*)d_in[2];
    const int*   dst_idx  = (const int*)d_in[3];
    const int*   path_len = (const int*)d_in[4];
    int P = in_sizes[2];
    int n = in_sizes[0] / 128;                      // N = 6000
    long long totalCells = (long long)n * n;        // 36,000,000
    int nblk = (P + TILE - 1) / TILE;               // 652

    // Fast path ws layout: recs [nblk*TILE u32] (32.1 MB) |
    //                      startsW [nblk*NPACK u32] (2.9 MB)
    size_t needFast = (size_t)nblk * TILE * 4u
                    + (size_t)nblk * NPACK * 4u;

    if (ws_size >= needFast && nblk <= MRG_THREADS) {
        unsigned int* recs    = (unsigned int*)d_ws;
        unsigned int* startsW = recs + (size_t)nblk * TILE;

        se_bin_local<<<nblk, BIN_THREADS, 0, stream>>>(
            src_idx, dst_idx, path_len, recs, startsW, P, n);

        se_merge3<<<NBUCK, MRG_THREADS, 0, stream>>>(
            startsW, recs, b, (float*)d_out, totalCells, nblk);
    } else {
        // R9 fallback: records staged in d_out at global per-bucket bases
        unsigned int*   countsW = (unsigned int*)d_ws;
        unsigned short* basesT  = (unsigned short*)(countsW + (size_t)nblk * NPACK);

        se_hist<<<nblk, BIN_THREADS, 0, stream>>>(src_idx, dst_idx, countsW, P, n);
        se_scan<<<(NBUCK + SCAN_TB - 1) / SCAN_TB, 256, 0, stream>>>(countsW, basesT, nblk);
        se_bin5<<<nblk, BIN_THREADS, 0, stream>>>(
            src_idx, dst_idx, path_len, (unsigned int*)d_out, countsW, P, n);
        se_merge<<<NBUCK, MRG_THREADS, 0, stream>>>(basesT, b, (float*)d_out,
                                                    totalCells, nblk);
    }
}